// Round 9
// baseline (556.851 us; speedup 1.0000x reference)
//
#include <hip/hip_runtime.h>
#include <hip/hip_bf16.h>
#include <math.h>

#define P_CHUNK 8192
#define NBKT 1024   // LDS bins; used buckets = ceil(N/128)

typedef float f4 __attribute__((ext_vector_type(4)));

__device__ __forceinline__ float lrelu(float x){ return x < 0.f ? 0.2f*x : x; }
__device__ __forceinline__ float elu_(float x){ return x > 0.f ? x : expm1f(x); }

// ---------------- CSR build: bucket sort, LDS-privatized counting ----------------
__global__ __launch_bounds__(256) void p1hist(const int* __restrict__ ei, int E, int Etot,
                                              int* __restrict__ totals){
  __shared__ int lh[NBKT];
  int tid = threadIdx.x;
  for (int t = tid; t < NBKT; t += 256) lh[t] = 0;
  __syncthreads();
  int base = blockIdx.x * P_CHUNK;
  for (int j = 0; j < P_CHUNK; j += 256){
    int i = base + j + tid;
    if (i < Etot){
      int dst = (i < E) ? ei[E + i] : (i - E);
      atomicAdd(&lh[dst >> 7], 1);
    }
  }
  __syncthreads();
  for (int t = tid; t < NBKT; t += 256){
    int v = lh[t];
    if (v) atomicAdd(&totals[t], v);
  }
}

__global__ __launch_bounds__(256) void p2scan(const int* __restrict__ totals,
                                              int* __restrict__ bbase, int* __restrict__ bcur,
                                              int Etot, int* __restrict__ off, int N){
  __shared__ int wsum[4];
  __shared__ int runsh;
  int tid = threadIdx.x, lane = tid & 63, w = tid >> 6;
  if (tid == 0) runsh = 0;
  __syncthreads();
  for (int c = 0; c < NBKT; c += 256){
    int v = totals[c + tid];
    int x = v;
    #pragma unroll
    for (int d = 1; d < 64; d <<= 1){ int y = __shfl_up(x, d); if (lane >= d) x += y; }
    if (lane == 63) wsum[w] = x;
    __syncthreads();
    int wpre = 0;
    for (int i = 0; i < w; i++) wpre += wsum[i];
    int run = runsh;
    int excl = run + wpre + x - v;
    bbase[c + tid] = excl;
    bcur[c + tid]  = excl;
    __syncthreads();
    if (tid == 0) runsh = run + wsum[0] + wsum[1] + wsum[2] + wsum[3];
    __syncthreads();
  }
  if (tid == 0){ bbase[NBKT] = Etot; off[N] = Etot; }
}

// P3: slab reservation + LDS-rank scatter of packed (src | dlow<<17)
__global__ __launch_bounds__(256) void p3scatter(const int* __restrict__ ei, int E, int Etot,
                                                 int* __restrict__ bcur, int* __restrict__ tmp){
  __shared__ int lh[NBKT];
  __shared__ int lbase[NBKT];
  int tid = threadIdx.x;
  for (int t = tid; t < NBKT; t += 256) lh[t] = 0;
  __syncthreads();
  int base = blockIdx.x * P_CHUNK;
  for (int j = 0; j < P_CHUNK; j += 256){
    int i = base + j + tid;
    if (i < Etot){
      int dst = (i < E) ? ei[E + i] : (i - E);
      atomicAdd(&lh[dst >> 7], 1);
    }
  }
  __syncthreads();
  for (int t = tid; t < NBKT; t += 256){
    int v = lh[t];
    lbase[t] = v ? atomicAdd(&bcur[t], v) : 0;
  }
  __syncthreads();
  for (int t = tid; t < NBKT; t += 256) lh[t] = 0;
  __syncthreads();
  for (int j = 0; j < P_CHUNK; j += 256){
    int i = base + j + tid;
    if (i < Etot){
      int s, d;
      if (i < E){ s = ei[i]; d = ei[E + i]; } else { s = i - E; d = i - E; }
      int b = d >> 7;
      int r = atomicAdd(&lh[b], 1);
      tmp[lbase[b] + r] = s | ((d & 127) << 17);
    }
  }
}

// P4: one block per bucket — exact per-dst offsets + src scatter
__global__ __launch_bounds__(256) void p4local(const int* __restrict__ tmp,
                                               const int* __restrict__ bbase,
                                               int* __restrict__ off, int* __restrict__ srcs, int N){
  __shared__ int cnt[128];
  __shared__ int offL[128];
  int b = blockIdx.x, tid = threadIdx.x;
  int e0 = bbase[b], e1 = bbase[b + 1];
  if (tid < 128) cnt[tid] = 0;
  __syncthreads();
  for (int j = e0 + tid; j < e1; j += 256)
    atomicAdd(&cnt[(tmp[j] >> 17) & 127], 1);
  __syncthreads();
  if (tid < 64){
    int v0 = cnt[2*tid], v1 = cnt[2*tid + 1];
    int p = v0 + v1;
    int x = p;
    #pragma unroll
    for (int d = 1; d < 64; d <<= 1){ int y = __shfl_up(x, d); if (tid >= d) x += y; }
    int excl = x - p;
    offL[2*tid]     = excl;
    offL[2*tid + 1] = excl + v0;
  }
  __syncthreads();
  if (tid < 128){
    int gd = b*128 + tid;
    if (gd < N) off[gd] = e0 + offL[tid];
    cnt[tid] = 0;
  }
  __syncthreads();
  for (int j = e0 + tid; j < e1; j += 256){
    int e = tmp[j];
    int d = (e >> 17) & 127;
    int r = atomicAdd(&cnt[d], 1);
    srcs[e0 + offL[d] + r] = e & 0x1FFFF;
  }
}

// ---------------- fused (gather) + GEMM(128x128) + attention-logit reductions ----------------
// 64-row tile, 256 threads = 8 row-groups x 32 col-groups; thread owns 8x4.
// xs natural layout [row][k] (coalesced global + conflict-free LDS float4, no
// transpose); inner loop vectorizes over k-quads: 12 b128 reads / 128 FMA.
template<int H, bool GATHER>
__global__ __launch_bounds__(256) void gemm_al(
    const float* __restrict__ X, const int* __restrict__ idx,
    const float* __restrict__ W, const float* __restrict__ asrc,
    const float* __restrict__ adst, float* __restrict__ Hout,
    float* __restrict__ als, float* __restrict__ ald, int n)
{
  __shared__ float xs[64][132];     // [row][k], pad 132 keeps quads bank-spread
  __shared__ float wch[32][128];    // [k within chunk][col]
  int tid = threadIdx.x;
  int tr = tid >> 5, tc = tid & 31;
  int r8 = tr*8, c4 = tc*4;
  int row0 = blockIdx.x * 64;

  // stage X natural: 64 rows x 32 quads, coalesced, vector LDS writes
  #pragma unroll
  for (int j=0;j<8;j++){
    int e = tid + j*256;
    int r = e >> 5, cq = e & 31;
    int gr = row0 + r;
    f4 v = (f4)(0.f);
    if (gr < n){
      int srow = GATHER ? idx[gr] : gr;
      v = *reinterpret_cast<const f4*>(&X[(size_t)srow*128 + cq*4]);
    }
    *reinterpret_cast<f4*>(&xs[r][cq*4]) = v;
  }

  float acc[8][4];
  #pragma unroll
  for (int r=0;r<8;r++)
    #pragma unroll
    for (int i=0;i<4;i++) acc[r][i] = 0.f;

  for (int kc=0;kc<4;kc++){
    __syncthreads();
    #pragma unroll
    for (int j=0;j<4;j++){
      int e = tid + j*256;
      int r = e>>5, cq = e&31;
      *reinterpret_cast<f4*>(&wch[r][cq*4]) =
        *reinterpret_cast<const f4*>(&W[(size_t)(kc*32+r)*128 + cq*4]);
    }
    __syncthreads();
    #pragma unroll
    for (int kq=0;kq<8;kq++){
      int k0 = kc*32 + kq*4;
      f4 xv[8], wv[4];
      #pragma unroll
      for (int i=0;i<8;i++) xv[i] = *reinterpret_cast<const f4*>(&xs[r8+i][k0]);
      #pragma unroll
      for (int kk=0;kk<4;kk++) wv[kk] = *reinterpret_cast<const f4*>(&wch[kq*4+kk][c4]);
      #pragma unroll
      for (int kk=0;kk<4;kk++)
        #pragma unroll
        for (int i=0;i<8;i++)
          #pragma unroll
          for (int j=0;j<4;j++)
            acc[i][j] = fmaf(xv[i][kk], wv[kk][j], acc[i][j]);
    }
  }

  // epilogue: store H rows + attention-logit reductions
  const f4 asv = *reinterpret_cast<const f4*>(&asrc[c4]);
  const f4 adv = *reinterpret_cast<const f4*>(&adst[c4]);
  const int GT = 32 / H;            // tc-threads per head (H=4 -> 8, H=1 -> 32)
  int hh = tc / GT;

  #pragma unroll
  for (int r=0;r<8;r++){
    int gr = row0 + r8 + r;
    if (gr < n){
      f4 o = { acc[r][0], acc[r][1], acc[r][2], acc[r][3] };
      *reinterpret_cast<f4*>(&Hout[(size_t)gr*128 + c4]) = o;
    }
    float ps = acc[r][0]*asv[0] + acc[r][1]*asv[1] + acc[r][2]*asv[2] + acc[r][3]*asv[3];
    float pd = acc[r][0]*adv[0] + acc[r][1]*adv[1] + acc[r][2]*adv[2] + acc[r][3]*adv[3];
    #pragma unroll
    for (int m=1;m<GT;m<<=1){ ps += __shfl_xor(ps,m); pd += __shfl_xor(pd,m); }
    if ((tc & (GT-1)) == 0 && gr < n){
      als[(size_t)gr*H + hh] = ps;
      ald[(size_t)gr*H + hh] = pd;
    }
  }
}

// ---------------- per-dst segment softmax + weighted aggregation ----------------
template<int H>
__global__ __launch_bounds__(256) void aggr(
    const float* __restrict__ h, const float* __restrict__ als,
    const float* __restrict__ ald, const int* __restrict__ srcs,
    const int* __restrict__ off, const float* __restrict__ bias,
    float* __restrict__ out, int n)
{
  __shared__ float s_p[4][64*H];
  __shared__ int   s_s[4][64];
  int tid = threadIdx.x;
  int wid = tid >> 6, lane = tid & 63;
  int d = blockIdx.x*4 + wid;
  if (d >= n) return;
  int half = lane >> 5, ch = lane & 31;
  int c4 = ch*4;
  const int hh = (H==1) ? 0 : (ch >> 3);

  int s0 = off[d], s1 = off[d+1];

  float adv[H];
  #pragma unroll
  for (int q=0;q<H;q++) adv[q] = ald[(size_t)d*H + q];

  float m[H], ssum[H];
  #pragma unroll
  for (int q=0;q<H;q++){ m[q] = -INFINITY; ssum[q] = 0.f; }
  float a0=0.f, a1=0.f, a2=0.f, a3=0.f;

  for (int base = s0; base < s1; base += 64){
    int cl = s1 - base; if (cl > 64) cl = 64;

    int sv = 0;
    float e[H];
    if (lane < cl){
      sv = srcs[base + lane];
      #pragma unroll
      for (int q=0;q<H;q++) e[q] = lrelu(als[(size_t)sv*H + q] + adv[q]);
    } else {
      #pragma unroll
      for (int q=0;q<H;q++) e[q] = -INFINITY;
    }

    float cm[H];
    #pragma unroll
    for (int q=0;q<H;q++) cm[q] = e[q];
    #pragma unroll
    for (int sh=1; sh<64; sh<<=1){
      #pragma unroll
      for (int q=0;q<H;q++) cm[q] = fmaxf(cm[q], __shfl_xor(cm[q], sh));
    }

    float p[H], sc[H];
    #pragma unroll
    for (int q=0;q<H;q++){
      float nm = fmaxf(m[q], cm[q]);
      sc[q] = __expf(m[q] - nm);
      ssum[q] *= sc[q];
      m[q] = nm;
      p[q] = __expf(e[q] - nm);
    }
    float schh = sc[0];
    #pragma unroll
    for (int q=1;q<H;q++) schh = (hh==q) ? sc[q] : schh;
    a0 *= schh; a1 *= schh; a2 *= schh; a3 *= schh;

    float cs[H];
    #pragma unroll
    for (int q=0;q<H;q++) cs[q] = p[q];
    #pragma unroll
    for (int sh=1; sh<64; sh<<=1){
      #pragma unroll
      for (int q=0;q<H;q++) cs[q] += __shfl_xor(cs[q], sh);
    }
    #pragma unroll
    for (int q=0;q<H;q++) ssum[q] += cs[q];

    #pragma unroll
    for (int q=0;q<H;q++) s_p[wid][lane*H + q] = p[q];
    s_s[wid][lane] = sv;

    for (int j = half; j < cl; j += 2){
      int s = s_s[wid][j];
      float w = s_p[wid][j*H + hh];
      const float4 hv = *reinterpret_cast<const float4*>(&h[(size_t)s*128 + c4]);
      a0 = fmaf(w, hv.x, a0);
      a1 = fmaf(w, hv.y, a1);
      a2 = fmaf(w, hv.z, a2);
      a3 = fmaf(w, hv.w, a3);
    }
  }

  a0 += __shfl_xor(a0, 32);
  a1 += __shfl_xor(a1, 32);
  a2 += __shfl_xor(a2, 32);
  a3 += __shfl_xor(a3, 32);

  float den = ssum[0];
  #pragma unroll
  for (int q=1;q<H;q++) den = (hh==q) ? ssum[q] : den;
  float inv = 1.f / den;

  if (half == 0){
    const f4 bv = *reinterpret_cast<const f4*>(&bias[c4]);
    f4 o;
    o[0] = elu_(a0*inv + bv[0]);
    o[1] = elu_(a1*inv + bv[1]);
    o[2] = elu_(a2*inv + bv[2]);
    o[3] = elu_(a3*inv + bv[3]);
    // non-temporal: don't let out-writes evict h from L2/L3 (h is gather-hot)
    __builtin_nontemporal_store(o, reinterpret_cast<f4*>(&out[(size_t)d*128 + c4]));
  }
}

// ---------------- global mean pool (batch is sorted) ----------------
__global__ __launch_bounds__(256) void kpool(const float* __restrict__ act,
    const int* __restrict__ batch, int n, float* __restrict__ pool)
{
  __shared__ int sb[2];
  __shared__ float part[128];
  int g = blockIdx.x, tid = threadIdx.x;
  if (tid == 0){
    int lo=0, hi=n;
    while (lo<hi){ int mid=(lo+hi)>>1; if (batch[mid] < g) lo=mid+1; else hi=mid; }
    sb[0]=lo;
    int lo2=lo, hi2=n;
    while (lo2<hi2){ int mid=(lo2+hi2)>>1; if (batch[mid] < g+1) lo2=mid+1; else hi2=mid; }
    sb[1]=lo2;
  }
  __syncthreads();
  int lo=sb[0], hi=sb[1];
  int c = tid & 127, half = tid >> 7;
  float acc = 0.f;
  for (int i=lo+half; i<hi; i+=2) acc += act[(size_t)i*128 + c];
  if (half == 0) part[c] = acc;
  __syncthreads();
  if (half == 1) part[c] += acc;
  __syncthreads();
  if (half == 0){
    float cnt = (float)(hi-lo);
    pool[(size_t)g*128 + c] = part[c] / fmaxf(cnt, 1.f);
  }
}

// ---------------- classifier head ----------------
__global__ __launch_bounds__(64) void kclassify(const float* __restrict__ pool,
    const float* __restrict__ Wc1, const float* __restrict__ bc1,
    const float* __restrict__ Wc2, const float* __restrict__ bc2,
    float* __restrict__ logits)
{
  int g = blockIdx.x, j = threadIdx.x;
  const float* hp = pool + (size_t)g*128;
  float t = bc1[j];
  #pragma unroll 8
  for (int c=0;c<128;c++) t = fmaf(hp[c], Wc1[c*64+j], t);
  t = fmaxf(t, 0.f) * Wc2[j];
  for (int m=1;m<64;m<<=1) t += __shfl_xor(t, m);
  if (j==0) logits[g] = t + bc2[0];
}

extern "C" void kernel_launch(void* const* d_in, const int* in_sizes, int n_in,
                              void* d_out, int out_size, void* d_ws, size_t ws_size,
                              hipStream_t stream)
{
  const int*   x_lex = (const int*)d_in[0];
  const int*   ei    = (const int*)d_in[1];
  const int*   batch = (const int*)d_in[2];
  const float* emb   = (const float*)d_in[3];
  const float* W1    = (const float*)d_in[4];
  const float* a1s   = (const float*)d_in[5];
  const float* a1d   = (const float*)d_in[6];
  const float* b1    = (const float*)d_in[7];
  const float* W2    = (const float*)d_in[8];
  const float* a2s   = (const float*)d_in[9];
  const float* a2d   = (const float*)d_in[10];
  const float* b2    = (const float*)d_in[11];
  const float* Wc1   = (const float*)d_in[12];
  const float* bc1   = (const float*)d_in[13];
  const float* Wc2   = (const float*)d_in[14];
  const float* bc2   = (const float*)d_in[15];

  int N = in_sizes[0];
  int E = in_sizes[1] / 2;
  int Etot = E + N;
  const int G = 256;

  char* p = (char*)d_ws;
  float* hbuf   = (float*)p;          p += (size_t)N*128*4;
  float* act    = (float*)p;          p += (size_t)N*128*4;
  float* als    = (float*)p;          p += (size_t)N*4*4;
  float* ald    = (float*)p;          p += (size_t)N*4*4;
  int*   off    = (int*)p;            p += (size_t)(N+1)*4;
  int*   srcs   = (int*)p;            p += (size_t)Etot*4;
  int*   totals = (int*)p;            p += NBKT*4;
  int*   bbase  = (int*)p;            p += (NBKT+1)*4;
  int*   bcur   = (int*)p;            /* NBKT ints */
  int*   tmp    = (int*)hbuf;         // aliases hbuf: CSR build finishes before gemm writes hbuf

  // ---- CSR build (bucket sort, shared by both GAT layers) ----
  hipMemsetAsync(totals, 0, NBKT*4, stream);
  int nblk = (Etot + P_CHUNK - 1) / P_CHUNK;
  int nb   = (N + 127) / 128;
  p1hist   <<<nblk,256,0,stream>>>(ei, E, Etot, totals);
  p2scan   <<<1,   256,0,stream>>>(totals, bbase, bcur, Etot, off, N);
  p3scatter<<<nblk,256,0,stream>>>(ei, E, Etot, bcur, tmp);
  p4local  <<<nb,  256,0,stream>>>(tmp, bbase, off, srcs, N);

  // ---- layer 1: h = emb[x_lex] @ W1, 4 heads ----
  int gb = (N + 63)/64;
  gemm_al<4,true ><<<gb,256,0,stream>>>(emb, x_lex, W1, a1s, a1d, hbuf, als, ald, N);
  aggr<4><<<(N+3)/4,256,0,stream>>>(hbuf, als, ald, srcs, off, b1, act, N);

  // ---- layer 2: h2 = act @ W2, 1 head ----
  gemm_al<1,false><<<gb,256,0,stream>>>(act, nullptr, W2, a2s, a2d, hbuf, als, ald, N);
  aggr<1><<<(N+3)/4,256,0,stream>>>(hbuf, als, ald, srcs, off, b2, act, N);

  // ---- pool + classifier ----
  float* out = (float*)d_out;
  kpool<<<G,256,0,stream>>>(act, batch, N, out + G);
  kclassify<<<G,64,0,stream>>>(out + G, Wc1, bc1, Wc2, bc2, out);
}

// Round 10
// 516.605 us; speedup vs baseline: 1.0779x; 1.0779x over previous
//
#include <hip/hip_runtime.h>
#include <hip/hip_bf16.h>
#include <math.h>

#define P_CHUNK 8192
#define NBKT 1024   // bucket = dst>>7; used buckets = ceil(N/128)
#define CAP  4096   // slab capacity per bucket (max real bucket ~2350)

typedef float f4 __attribute__((ext_vector_type(4)));

__device__ __forceinline__ float lrelu(float x){ return x < 0.f ? 0.2f*x : x; }
__device__ __forceinline__ float elu_(float x){ return x > 0.f ? x : expm1f(x); }

// ---------------- CSR build: slab bucket sort (no pre-count pass) ----------------
// P3: per-block LDS histogram -> slab reservation in bcur -> LDS-rank scatter of
// packed (src | dlow<<17) into fixed-capacity bucket slabs.
__global__ __launch_bounds__(256) void p3scatter(const int* __restrict__ ei, int E, int Etot,
                                                 int* __restrict__ bcur, int* __restrict__ tmp){
  __shared__ int lh[NBKT];
  __shared__ int lbase[NBKT];
  int tid = threadIdx.x;
  for (int t = tid; t < NBKT; t += 256) lh[t] = 0;
  __syncthreads();
  int base = blockIdx.x * P_CHUNK;
  for (int j = 0; j < P_CHUNK; j += 256){
    int i = base + j + tid;
    if (i < Etot){
      int dst = (i < E) ? ei[E + i] : (i - E);
      atomicAdd(&lh[dst >> 7], 1);
    }
  }
  __syncthreads();
  for (int t = tid; t < NBKT; t += 256){
    int v = lh[t];
    lbase[t] = v ? atomicAdd(&bcur[t], v) : 0;
  }
  __syncthreads();
  for (int t = tid; t < NBKT; t += 256) lh[t] = 0;   // reuse as local cursor
  __syncthreads();
  for (int j = 0; j < P_CHUNK; j += 256){
    int i = base + j + tid;
    if (i < Etot){
      int s, d;
      if (i < E){ s = ei[i]; d = ei[E + i]; } else { s = i - E; d = i - E; }
      int b = d >> 7;
      int r = atomicAdd(&lh[b], 1);
      tmp[b*CAP + lbase[b] + r] = s | ((d & 127) << 17);
    }
  }
}

// P2: exclusive scan of bucket counts (bcur) -> bbase; off[N]=Etot
__global__ __launch_bounds__(256) void p2scan(const int* __restrict__ bcur,
                                              int* __restrict__ bbase,
                                              int Etot, int* __restrict__ off, int N){
  __shared__ int wsum[4];
  __shared__ int runsh;
  int tid = threadIdx.x, lane = tid & 63, w = tid >> 6;
  if (tid == 0) runsh = 0;
  __syncthreads();
  for (int c = 0; c < NBKT; c += 256){
    int v = bcur[c + tid];
    int x = v;
    #pragma unroll
    for (int d = 1; d < 64; d <<= 1){ int y = __shfl_up(x, d); if (lane >= d) x += y; }
    if (lane == 63) wsum[w] = x;
    __syncthreads();
    int wpre = 0;
    for (int i = 0; i < w; i++) wpre += wsum[i];
    int run = runsh;
    bbase[c + tid] = run + wpre + x - v;
    __syncthreads();
    if (tid == 0) runsh = run + wsum[0] + wsum[1] + wsum[2] + wsum[3];
    __syncthreads();
  }
  if (tid == 0) off[N] = Etot;
}

// P4: one block per bucket — exact per-dst offsets + src scatter from its slab
__global__ __launch_bounds__(256) void p4local(const int* __restrict__ tmp,
                                               const int* __restrict__ bbase,
                                               const int* __restrict__ bcnt,
                                               int* __restrict__ off, int* __restrict__ srcs, int N){
  __shared__ int cnt[128];
  __shared__ int offL[128];
  int b = blockIdx.x, tid = threadIdx.x;
  int e0 = bbase[b];
  int ne = bcnt[b];
  const int* slab = tmp + (size_t)b*CAP;
  if (tid < 128) cnt[tid] = 0;
  __syncthreads();
  for (int j = tid; j < ne; j += 256)
    atomicAdd(&cnt[(slab[j] >> 17) & 127], 1);
  __syncthreads();
  if (tid < 64){
    int v0 = cnt[2*tid], v1 = cnt[2*tid + 1];
    int p = v0 + v1;
    int x = p;
    #pragma unroll
    for (int d = 1; d < 64; d <<= 1){ int y = __shfl_up(x, d); if (tid >= d) x += y; }
    int excl = x - p;
    offL[2*tid]     = excl;
    offL[2*tid + 1] = excl + v0;
  }
  __syncthreads();
  if (tid < 128){
    int gd = b*128 + tid;
    if (gd < N) off[gd] = e0 + offL[tid];
    cnt[tid] = 0;
  }
  __syncthreads();
  for (int j = tid; j < ne; j += 256){
    int e = slab[j];
    int d = (e >> 17) & 127;
    int r = atomicAdd(&cnt[d], 1);
    srcs[e0 + offL[d] + r] = e & 0x1FFFF;
  }
}

// ---------------- fused (gather) + GEMM(128x128) + attention-logit reductions ----------------
// 64-row tile, 256 threads = 8 row-groups x 32 col-groups; each thread owns 8x4.
// X transposed in LDS; per kk: 3x ds_read_b128 per 32 FMA -> VALU-bound. (r8 version)
template<int H, bool GATHER>
__global__ __launch_bounds__(256) void gemm_al(
    const float* __restrict__ X, const int* __restrict__ idx,
    const float* __restrict__ W, const float* __restrict__ asrc,
    const float* __restrict__ adst, float* __restrict__ Hout,
    float* __restrict__ als, float* __restrict__ ald, int n)
{
  __shared__ float xs[128][68];
  __shared__ float wch[32][128];
  int tid = threadIdx.x;
  int tr = tid >> 5, tc = tid & 31;
  int r8 = tr*8, c4 = tc*4;
  int row0 = blockIdx.x * 64;

  #pragma unroll
  for (int j=0;j<8;j++){
    int e = tid + j*256;
    int r = e >> 5, cq = e & 31;
    int gr = row0 + r;
    float4 v = make_float4(0.f,0.f,0.f,0.f);
    if (gr < n){
      int srow = GATHER ? idx[gr] : gr;
      v = *reinterpret_cast<const float4*>(&X[(size_t)srow*128 + cq*4]);
    }
    xs[cq*4+0][r] = v.x;
    xs[cq*4+1][r] = v.y;
    xs[cq*4+2][r] = v.z;
    xs[cq*4+3][r] = v.w;
  }

  float acc[8][4];
  #pragma unroll
  for (int r=0;r<8;r++)
    #pragma unroll
    for (int i=0;i<4;i++) acc[r][i] = 0.f;

  for (int kc=0;kc<4;kc++){
    __syncthreads();
    #pragma unroll
    for (int j=0;j<4;j++){
      int e = tid + j*256;
      int r = e>>5, cq = e&31;
      *reinterpret_cast<float4*>(&wch[r][cq*4]) =
        *reinterpret_cast<const float4*>(&W[(size_t)(kc*32+r)*128 + cq*4]);
    }
    __syncthreads();
    #pragma unroll
    for (int kk=0;kk<32;kk++){
      int k = kc*32+kk;
      const float4 x0 = *reinterpret_cast<const float4*>(&xs[k][r8]);
      const float4 x1 = *reinterpret_cast<const float4*>(&xs[k][r8+4]);
      const float4 wv = *reinterpret_cast<const float4*>(&wch[kk][c4]);
      acc[0][0]=fmaf(x0.x,wv.x,acc[0][0]); acc[0][1]=fmaf(x0.x,wv.y,acc[0][1]);
      acc[0][2]=fmaf(x0.x,wv.z,acc[0][2]); acc[0][3]=fmaf(x0.x,wv.w,acc[0][3]);
      acc[1][0]=fmaf(x0.y,wv.x,acc[1][0]); acc[1][1]=fmaf(x0.y,wv.y,acc[1][1]);
      acc[1][2]=fmaf(x0.y,wv.z,acc[1][2]); acc[1][3]=fmaf(x0.y,wv.w,acc[1][3]);
      acc[2][0]=fmaf(x0.z,wv.x,acc[2][0]); acc[2][1]=fmaf(x0.z,wv.y,acc[2][1]);
      acc[2][2]=fmaf(x0.z,wv.z,acc[2][2]); acc[2][3]=fmaf(x0.z,wv.w,acc[2][3]);
      acc[3][0]=fmaf(x0.w,wv.x,acc[3][0]); acc[3][1]=fmaf(x0.w,wv.y,acc[3][1]);
      acc[3][2]=fmaf(x0.w,wv.z,acc[3][2]); acc[3][3]=fmaf(x0.w,wv.w,acc[3][3]);
      acc[4][0]=fmaf(x1.x,wv.x,acc[4][0]); acc[4][1]=fmaf(x1.x,wv.y,acc[4][1]);
      acc[4][2]=fmaf(x1.x,wv.z,acc[4][2]); acc[4][3]=fmaf(x1.x,wv.w,acc[4][3]);
      acc[5][0]=fmaf(x1.y,wv.x,acc[5][0]); acc[5][1]=fmaf(x1.y,wv.y,acc[5][1]);
      acc[5][2]=fmaf(x1.y,wv.z,acc[5][2]); acc[5][3]=fmaf(x1.y,wv.w,acc[5][3]);
      acc[6][0]=fmaf(x1.z,wv.x,acc[6][0]); acc[6][1]=fmaf(x1.z,wv.y,acc[6][1]);
      acc[6][2]=fmaf(x1.z,wv.z,acc[6][2]); acc[6][3]=fmaf(x1.z,wv.w,acc[6][3]);
      acc[7][0]=fmaf(x1.w,wv.x,acc[7][0]); acc[7][1]=fmaf(x1.w,wv.y,acc[7][1]);
      acc[7][2]=fmaf(x1.w,wv.z,acc[7][2]); acc[7][3]=fmaf(x1.w,wv.w,acc[7][3]);
    }
  }

  const float4 asv = *reinterpret_cast<const float4*>(&asrc[c4]);
  const float4 adv = *reinterpret_cast<const float4*>(&adst[c4]);
  const int GT = 32 / H;
  int hh = tc / GT;

  #pragma unroll
  for (int r=0;r<8;r++){
    int gr = row0 + r8 + r;
    if (gr < n){
      *reinterpret_cast<float4*>(&Hout[(size_t)gr*128 + c4]) =
        make_float4(acc[r][0], acc[r][1], acc[r][2], acc[r][3]);
    }
    float ps = acc[r][0]*asv.x + acc[r][1]*asv.y + acc[r][2]*asv.z + acc[r][3]*asv.w;
    float pd = acc[r][0]*adv.x + acc[r][1]*adv.y + acc[r][2]*adv.z + acc[r][3]*adv.w;
    #pragma unroll
    for (int m=1;m<GT;m<<=1){ ps += __shfl_xor(ps,m); pd += __shfl_xor(pd,m); }
    if ((tc & (GT-1)) == 0 && gr < n){
      als[(size_t)gr*H + hh] = ps;
      ald[(size_t)gr*H + hh] = pd;
    }
  }
}

// ---------------- per-dst segment softmax + weighted aggregation ----------------
template<int H>
__global__ __launch_bounds__(256) void aggr(
    const float* __restrict__ h, const float* __restrict__ als,
    const float* __restrict__ ald, const int* __restrict__ srcs,
    const int* __restrict__ off, const float* __restrict__ bias,
    float* __restrict__ out, int n)
{
  __shared__ float s_p[4][64*H];
  __shared__ int   s_s[4][64];
  int tid = threadIdx.x;
  int wid = tid >> 6, lane = tid & 63;
  int d = blockIdx.x*4 + wid;
  if (d >= n) return;
  int half = lane >> 5, ch = lane & 31;
  int c4 = ch*4;
  const int hh = (H==1) ? 0 : (ch >> 3);

  int s0 = off[d], s1 = off[d+1];

  float adv[H];
  #pragma unroll
  for (int q=0;q<H;q++) adv[q] = ald[(size_t)d*H + q];

  float m[H], ssum[H];
  #pragma unroll
  for (int q=0;q<H;q++){ m[q] = -INFINITY; ssum[q] = 0.f; }
  float a0=0.f, a1=0.f, a2=0.f, a3=0.f;

  for (int base = s0; base < s1; base += 64){
    int cl = s1 - base; if (cl > 64) cl = 64;

    int sv = 0;
    float e[H];
    if (lane < cl){
      sv = srcs[base + lane];
      #pragma unroll
      for (int q=0;q<H;q++) e[q] = lrelu(als[(size_t)sv*H + q] + adv[q]);
    } else {
      #pragma unroll
      for (int q=0;q<H;q++) e[q] = -INFINITY;
    }

    float cm[H];
    #pragma unroll
    for (int q=0;q<H;q++) cm[q] = e[q];
    #pragma unroll
    for (int sh=1; sh<64; sh<<=1){
      #pragma unroll
      for (int q=0;q<H;q++) cm[q] = fmaxf(cm[q], __shfl_xor(cm[q], sh));
    }

    float p[H], sc[H];
    #pragma unroll
    for (int q=0;q<H;q++){
      float nm = fmaxf(m[q], cm[q]);
      sc[q] = __expf(m[q] - nm);
      ssum[q] *= sc[q];
      m[q] = nm;
      p[q] = __expf(e[q] - nm);
    }
    float schh = sc[0];
    #pragma unroll
    for (int q=1;q<H;q++) schh = (hh==q) ? sc[q] : schh;
    a0 *= schh; a1 *= schh; a2 *= schh; a3 *= schh;

    float cs[H];
    #pragma unroll
    for (int q=0;q<H;q++) cs[q] = p[q];
    #pragma unroll
    for (int sh=1; sh<64; sh<<=1){
      #pragma unroll
      for (int q=0;q<H;q++) cs[q] += __shfl_xor(cs[q], sh);
    }
    #pragma unroll
    for (int q=0;q<H;q++) ssum[q] += cs[q];

    #pragma unroll
    for (int q=0;q<H;q++) s_p[wid][lane*H + q] = p[q];
    s_s[wid][lane] = sv;

    for (int j = half; j < cl; j += 2){
      int s = s_s[wid][j];
      float w = s_p[wid][j*H + hh];
      const float4 hv = *reinterpret_cast<const float4*>(&h[(size_t)s*128 + c4]);
      a0 = fmaf(w, hv.x, a0);
      a1 = fmaf(w, hv.y, a1);
      a2 = fmaf(w, hv.z, a2);
      a3 = fmaf(w, hv.w, a3);
    }
  }

  a0 += __shfl_xor(a0, 32);
  a1 += __shfl_xor(a1, 32);
  a2 += __shfl_xor(a2, 32);
  a3 += __shfl_xor(a3, 32);

  float den = ssum[0];
  #pragma unroll
  for (int q=1;q<H;q++) den = (hh==q) ? ssum[q] : den;
  float inv = 1.f / den;

  if (half == 0){
    const float4 bv = *reinterpret_cast<const float4*>(&bias[c4]);
    float4 o;
    o.x = elu_(a0*inv + bv.x);
    o.y = elu_(a1*inv + bv.y);
    o.z = elu_(a2*inv + bv.z);
    o.w = elu_(a3*inv + bv.w);
    *reinterpret_cast<float4*>(&out[(size_t)d*128 + c4]) = o;
  }
}

// ---------------- global mean pool (batch is sorted) ----------------
__global__ __launch_bounds__(256) void kpool(const float* __restrict__ act,
    const int* __restrict__ batch, int n, float* __restrict__ pool)
{
  __shared__ int sb[2];
  __shared__ float part[128];
  int g = blockIdx.x, tid = threadIdx.x;
  if (tid == 0){
    int lo=0, hi=n;
    while (lo<hi){ int mid=(lo+hi)>>1; if (batch[mid] < g) lo=mid+1; else hi=mid; }
    sb[0]=lo;
    int lo2=lo, hi2=n;
    while (lo2<hi2){ int mid=(lo2+hi2)>>1; if (batch[mid] < g+1) lo2=mid+1; else hi2=mid; }
    sb[1]=lo2;
  }
  __syncthreads();
  int lo=sb[0], hi=sb[1];
  int c = tid & 127, half = tid >> 7;
  float acc = 0.f;
  for (int i=lo+half; i<hi; i+=2) acc += act[(size_t)i*128 + c];
  if (half == 0) part[c] = acc;
  __syncthreads();
  if (half == 1) part[c] += acc;
  __syncthreads();
  if (half == 0){
    float cnt = (float)(hi-lo);
    pool[(size_t)g*128 + c] = part[c] / fmaxf(cnt, 1.f);
  }
}

// ---------------- classifier head ----------------
__global__ __launch_bounds__(64) void kclassify(const float* __restrict__ pool,
    const float* __restrict__ Wc1, const float* __restrict__ bc1,
    const float* __restrict__ Wc2, const float* __restrict__ bc2,
    float* __restrict__ logits)
{
  int g = blockIdx.x, j = threadIdx.x;
  const float* hp = pool + (size_t)g*128;
  float t = bc1[j];
  #pragma unroll 8
  for (int c=0;c<128;c++) t = fmaf(hp[c], Wc1[c*64+j], t);
  t = fmaxf(t, 0.f) * Wc2[j];
  for (int m=1;m<64;m<<=1) t += __shfl_xor(t, m);
  if (j==0) logits[g] = t + bc2[0];
}

extern "C" void kernel_launch(void* const* d_in, const int* in_sizes, int n_in,
                              void* d_out, int out_size, void* d_ws, size_t ws_size,
                              hipStream_t stream)
{
  const int*   x_lex = (const int*)d_in[0];
  const int*   ei    = (const int*)d_in[1];
  const int*   batch = (const int*)d_in[2];
  const float* emb   = (const float*)d_in[3];
  const float* W1    = (const float*)d_in[4];
  const float* a1s   = (const float*)d_in[5];
  const float* a1d   = (const float*)d_in[6];
  const float* b1    = (const float*)d_in[7];
  const float* W2    = (const float*)d_in[8];
  const float* a2s   = (const float*)d_in[9];
  const float* a2d   = (const float*)d_in[10];
  const float* b2    = (const float*)d_in[11];
  const float* Wc1   = (const float*)d_in[12];
  const float* bc1   = (const float*)d_in[13];
  const float* Wc2   = (const float*)d_in[14];
  const float* bc2   = (const float*)d_in[15];

  int N = in_sizes[0];
  int E = in_sizes[1] / 2;
  int Etot = E + N;
  const int G = 256;

  char* p = (char*)d_ws;
  float* hbuf   = (float*)p;          p += (size_t)N*128*4;
  float* act    = (float*)p;          p += (size_t)N*128*4;
  float* als    = (float*)p;          p += (size_t)N*4*4;
  float* ald    = (float*)p;          p += (size_t)N*4*4;
  int*   off    = (int*)p;            p += (size_t)(N+1)*4;
  int*   srcs   = (int*)p;            p += (size_t)Etot*4;
  int*   bbase  = (int*)p;            p += (NBKT+1)*4;
  int*   bcur   = (int*)p;            /* NBKT ints */
  int*   tmp    = (int*)hbuf;         // slabs alias hbuf (CSR build precedes gemm)

  // ---- CSR build (slab bucket sort; p1 pre-count eliminated) ----
  hipMemsetAsync(bcur, 0, NBKT*4, stream);
  int nblk = (Etot + P_CHUNK - 1) / P_CHUNK;
  int nb   = (N + 127) / 128;
  p3scatter<<<nblk,256,0,stream>>>(ei, E, Etot, bcur, tmp);
  p2scan   <<<1,   256,0,stream>>>(bcur, bbase, Etot, off, N);
  p4local  <<<nb,  256,0,stream>>>(tmp, bbase, bcur, off, srcs, N);

  // ---- layer 1: h = emb[x_lex] @ W1, 4 heads ----
  int gb = (N + 63)/64;
  gemm_al<4,true ><<<gb,256,0,stream>>>(emb, x_lex, W1, a1s, a1d, hbuf, als, ald, N);
  aggr<4><<<(N+3)/4,256,0,stream>>>(hbuf, als, ald, srcs, off, b1, act, N);

  // ---- layer 2: h2 = act @ W2, 1 head ----
  gemm_al<1,false><<<gb,256,0,stream>>>(act, nullptr, W2, a2s, a2d, hbuf, als, ald, N);
  aggr<1><<<(N+3)/4,256,0,stream>>>(hbuf, als, ald, srcs, off, b2, act, N);

  // ---- pool + classifier ----
  float* out = (float*)d_out;
  kpool<<<G,256,0,stream>>>(act, batch, N, out + G);
  kclassify<<<G,64,0,stream>>>(out + G, Wc1, bc1, Wc2, bc2, out);
}

// Round 11
// 511.679 us; speedup vs baseline: 1.0883x; 1.0096x over previous
//
#include <hip/hip_runtime.h>
#include <hip/hip_bf16.h>
#include <math.h>

#define P_CHUNK 8192
#define NBKT 1024   // bucket = dst>>7; used buckets = ceil(N/128)
#define CAP  4096   // slab capacity per bucket (max real bucket ~2350)

typedef float f4 __attribute__((ext_vector_type(4)));

__device__ __forceinline__ float lrelu(float x){ return x < 0.f ? 0.2f*x : x; }
__device__ __forceinline__ float elu_(float x){ return x > 0.f ? x : expm1f(x); }

// ---------------- CSR build: slab bucket sort (no pre-count pass) ----------------
__global__ __launch_bounds__(256) void p3scatter(const int* __restrict__ ei, int E, int Etot,
                                                 int* __restrict__ bcur, int* __restrict__ tmp){
  __shared__ int lh[NBKT];
  __shared__ int lbase[NBKT];
  int tid = threadIdx.x;
  for (int t = tid; t < NBKT; t += 256) lh[t] = 0;
  __syncthreads();
  int base = blockIdx.x * P_CHUNK;
  for (int j = 0; j < P_CHUNK; j += 256){
    int i = base + j + tid;
    if (i < Etot){
      int dst = (i < E) ? ei[E + i] : (i - E);
      atomicAdd(&lh[dst >> 7], 1);
    }
  }
  __syncthreads();
  for (int t = tid; t < NBKT; t += 256){
    int v = lh[t];
    lbase[t] = v ? atomicAdd(&bcur[t], v) : 0;
  }
  __syncthreads();
  for (int t = tid; t < NBKT; t += 256) lh[t] = 0;   // reuse as local cursor
  __syncthreads();
  for (int j = 0; j < P_CHUNK; j += 256){
    int i = base + j + tid;
    if (i < Etot){
      int s, d;
      if (i < E){ s = ei[i]; d = ei[E + i]; } else { s = i - E; d = i - E; }
      int b = d >> 7;
      int r = atomicAdd(&lh[b], 1);
      tmp[b*CAP + lbase[b] + r] = s | ((d & 127) << 17);
    }
  }
}

__global__ __launch_bounds__(256) void p2scan(const int* __restrict__ bcur,
                                              int* __restrict__ bbase,
                                              int Etot, int* __restrict__ off, int N){
  __shared__ int wsum[4];
  __shared__ int runsh;
  int tid = threadIdx.x, lane = tid & 63, w = tid >> 6;
  if (tid == 0) runsh = 0;
  __syncthreads();
  for (int c = 0; c < NBKT; c += 256){
    int v = bcur[c + tid];
    int x = v;
    #pragma unroll
    for (int d = 1; d < 64; d <<= 1){ int y = __shfl_up(x, d); if (lane >= d) x += y; }
    if (lane == 63) wsum[w] = x;
    __syncthreads();
    int wpre = 0;
    for (int i = 0; i < w; i++) wpre += wsum[i];
    int run = runsh;
    bbase[c + tid] = run + wpre + x - v;
    __syncthreads();
    if (tid == 0) runsh = run + wsum[0] + wsum[1] + wsum[2] + wsum[3];
    __syncthreads();
  }
  if (tid == 0) off[N] = Etot;
}

__global__ __launch_bounds__(256) void p4local(const int* __restrict__ tmp,
                                               const int* __restrict__ bbase,
                                               const int* __restrict__ bcnt,
                                               int* __restrict__ off, int* __restrict__ srcs, int N){
  __shared__ int cnt[128];
  __shared__ int offL[128];
  int b = blockIdx.x, tid = threadIdx.x;
  int e0 = bbase[b];
  int ne = bcnt[b];
  const int* slab = tmp + (size_t)b*CAP;
  if (tid < 128) cnt[tid] = 0;
  __syncthreads();
  for (int j = tid; j < ne; j += 256)
    atomicAdd(&cnt[(slab[j] >> 17) & 127], 1);
  __syncthreads();
  if (tid < 64){
    int v0 = cnt[2*tid], v1 = cnt[2*tid + 1];
    int p = v0 + v1;
    int x = p;
    #pragma unroll
    for (int d = 1; d < 64; d <<= 1){ int y = __shfl_up(x, d); if (tid >= d) x += y; }
    int excl = x - p;
    offL[2*tid]     = excl;
    offL[2*tid + 1] = excl + v0;
  }
  __syncthreads();
  if (tid < 128){
    int gd = b*128 + tid;
    if (gd < N) off[gd] = e0 + offL[tid];
    cnt[tid] = 0;
  }
  __syncthreads();
  for (int j = tid; j < ne; j += 256){
    int e = slab[j];
    int d = (e >> 17) & 127;
    int r = atomicAdd(&cnt[d], 1);
    srcs[e0 + offL[d] + r] = e & 0x1FFFF;
  }
}

// ---------------- fused (gather) + GEMM(128x128) + attention-logit reductions ----------------
// 64-row tile, 256 threads = 8 row-groups x 32 col-groups; thread owns 8x4.
// xs natural [row][k] (conflict-free staging; row-broadcast reads). W read
// DIRECTLY from global (64KB, L2-resident, wave-coalesced) -> no wch staging,
// ONE barrier per block, 34KB LDS -> 4 blocks/CU.
template<int H, bool GATHER>
__global__ __launch_bounds__(256) void gemm_al(
    const float* __restrict__ X, const int* __restrict__ idx,
    const float* __restrict__ W, const float* __restrict__ asrc,
    const float* __restrict__ adst, float* __restrict__ Hout,
    float* __restrict__ als, float* __restrict__ ald, int n)
{
  __shared__ float xs[64][132];     // [row][k], pad 132
  int tid = threadIdx.x;
  int tr = tid >> 5, tc = tid & 31;
  int r8 = tr*8, c4 = tc*4;
  int row0 = blockIdx.x * 64;

  // stage X natural: coalesced global float4 -> contiguous LDS float4
  #pragma unroll
  for (int j=0;j<8;j++){
    int e = tid + j*256;
    int r = e >> 5, cq = e & 31;
    int gr = row0 + r;
    f4 v = (f4)(0.f);
    if (gr < n){
      int srow = GATHER ? idx[gr] : gr;
      v = *reinterpret_cast<const f4*>(&X[(size_t)srow*128 + cq*4]);
    }
    *reinterpret_cast<f4*>(&xs[r][cq*4]) = v;
  }
  __syncthreads();

  float acc[8][4];
  #pragma unroll
  for (int r=0;r<8;r++)
    #pragma unroll
    for (int i=0;i<4;i++) acc[r][i] = 0.f;

  #pragma unroll 4
  for (int kq=0;kq<32;kq++){
    int k0 = kq*4;
    f4 xv[8], wv[4];
    #pragma unroll
    for (int i=0;i<8;i++) xv[i] = *reinterpret_cast<const f4*>(&xs[r8+i][k0]);
    #pragma unroll
    for (int kk=0;kk<4;kk++) wv[kk] = *reinterpret_cast<const f4*>(&W[(size_t)(k0+kk)*128 + c4]);
    #pragma unroll
    for (int kk=0;kk<4;kk++)
      #pragma unroll
      for (int i=0;i<8;i++)
        #pragma unroll
        for (int j=0;j<4;j++)
          acc[i][j] = fmaf(xv[i][kk], wv[kk][j], acc[i][j]);
  }

  // epilogue: store H rows + attention-logit reductions
  const f4 asv = *reinterpret_cast<const f4*>(&asrc[c4]);
  const f4 adv = *reinterpret_cast<const f4*>(&adst[c4]);
  const int GT = 32 / H;            // tc-threads per head
  int hh = tc / GT;

  #pragma unroll
  for (int r=0;r<8;r++){
    int gr = row0 + r8 + r;
    if (gr < n){
      f4 o = { acc[r][0], acc[r][1], acc[r][2], acc[r][3] };
      *reinterpret_cast<f4*>(&Hout[(size_t)gr*128 + c4]) = o;
    }
    float ps = acc[r][0]*asv[0] + acc[r][1]*asv[1] + acc[r][2]*asv[2] + acc[r][3]*asv[3];
    float pd = acc[r][0]*adv[0] + acc[r][1]*adv[1] + acc[r][2]*adv[2] + acc[r][3]*adv[3];
    #pragma unroll
    for (int m=1;m<GT;m<<=1){ ps += __shfl_xor(ps,m); pd += __shfl_xor(pd,m); }
    if ((tc & (GT-1)) == 0 && gr < n){
      als[(size_t)gr*H + hh] = ps;
      ald[(size_t)gr*H + hh] = pd;
    }
  }
}

// ---------------- per-dst segment softmax + weighted aggregation ----------------
// One wave per dst. Softmax: lanes = edges (butterflies). Accumulate: 4
// quarter-groups x 16 lanes, each lane 8 channels -> 4 edges in flight/iter;
// combine with shfl_xor(16)+shfl_xor(32).
template<int H>
__global__ __launch_bounds__(256) void aggr(
    const float* __restrict__ h, const float* __restrict__ als,
    const float* __restrict__ ald, const int* __restrict__ srcs,
    const int* __restrict__ off, const float* __restrict__ bias,
    float* __restrict__ out, int n)
{
  __shared__ float s_p[4][64*H];
  __shared__ int   s_s[4][64];
  int tid = threadIdx.x;
  int wid = tid >> 6, lane = tid & 63;
  int d = blockIdx.x*4 + wid;
  if (d >= n) return;
  int q = lane >> 4, ch16 = lane & 15;
  int c8 = ch16 * 8;
  const int hh = (H==1) ? 0 : (ch16 >> 2);   // head owning channels c8..c8+7

  int s0 = off[d], s1 = off[d+1];

  float adv[H];
  #pragma unroll
  for (int qq=0;qq<H;qq++) adv[qq] = ald[(size_t)d*H + qq];

  float m[H], ssum[H];
  #pragma unroll
  for (int qq=0;qq<H;qq++){ m[qq] = -INFINITY; ssum[qq] = 0.f; }
  float a[8];
  #pragma unroll
  for (int i=0;i<8;i++) a[i] = 0.f;

  for (int base = s0; base < s1; base += 64){
    int cl = s1 - base; if (cl > 64) cl = 64;

    // --- softmax phase: lanes act as edges ---
    int sv = 0;
    float e[H];
    if (lane < cl){
      sv = srcs[base + lane];
      #pragma unroll
      for (int qq=0;qq<H;qq++) e[qq] = lrelu(als[(size_t)sv*H + qq] + adv[qq]);
    } else {
      #pragma unroll
      for (int qq=0;qq<H;qq++) e[qq] = -INFINITY;
    }

    float cm[H];
    #pragma unroll
    for (int qq=0;qq<H;qq++) cm[qq] = e[qq];
    #pragma unroll
    for (int sh=1; sh<64; sh<<=1){
      #pragma unroll
      for (int qq=0;qq<H;qq++) cm[qq] = fmaxf(cm[qq], __shfl_xor(cm[qq], sh));
    }

    float p[H], sc[H];
    #pragma unroll
    for (int qq=0;qq<H;qq++){
      float nm = fmaxf(m[qq], cm[qq]);
      sc[qq] = __expf(m[qq] - nm);
      ssum[qq] *= sc[qq];
      m[qq] = nm;
      p[qq] = __expf(e[qq] - nm);
    }
    float schh = sc[0];
    #pragma unroll
    for (int qq=1;qq<H;qq++) schh = (hh==qq) ? sc[qq] : schh;
    #pragma unroll
    for (int i=0;i<8;i++) a[i] *= schh;

    float cs[H];
    #pragma unroll
    for (int qq=0;qq<H;qq++) cs[qq] = p[qq];
    #pragma unroll
    for (int sh=1; sh<64; sh<<=1){
      #pragma unroll
      for (int qq=0;qq<H;qq++) cs[qq] += __shfl_xor(cs[qq], sh);
    }
    #pragma unroll
    for (int qq=0;qq<H;qq++) ssum[qq] += cs[qq];

    #pragma unroll
    for (int qq=0;qq<H;qq++) s_p[wid][lane*H + qq] = p[qq];
    s_s[wid][lane] = sv;

    // --- accumulate: 4 edges/iter (one per quarter), 8 ch/lane ---
    for (int j = q; j < cl; j += 4){
      int s = s_s[wid][j];
      float w = s_p[wid][j*H + hh];
      const f4 hv0 = *reinterpret_cast<const f4*>(&h[(size_t)s*128 + c8]);
      const f4 hv1 = *reinterpret_cast<const f4*>(&h[(size_t)s*128 + c8 + 4]);
      a[0] = fmaf(w, hv0[0], a[0]);
      a[1] = fmaf(w, hv0[1], a[1]);
      a[2] = fmaf(w, hv0[2], a[2]);
      a[3] = fmaf(w, hv0[3], a[3]);
      a[4] = fmaf(w, hv1[0], a[4]);
      a[5] = fmaf(w, hv1[1], a[5]);
      a[6] = fmaf(w, hv1[2], a[6]);
      a[7] = fmaf(w, hv1[3], a[7]);
    }
  }

  // combine quarters (same channels, same head across quarters)
  #pragma unroll
  for (int i=0;i<8;i++){
    a[i] += __shfl_xor(a[i], 16);
    a[i] += __shfl_xor(a[i], 32);
  }

  float den = ssum[0];
  #pragma unroll
  for (int qq=1;qq<H;qq++) den = (hh==qq) ? ssum[qq] : den;
  float inv = 1.f / den;

  if (q == 0){
    const f4 bv0 = *reinterpret_cast<const f4*>(&bias[c8]);
    const f4 bv1 = *reinterpret_cast<const f4*>(&bias[c8 + 4]);
    f4 o0, o1;
    o0[0] = elu_(a[0]*inv + bv0[0]);
    o0[1] = elu_(a[1]*inv + bv0[1]);
    o0[2] = elu_(a[2]*inv + bv0[2]);
    o0[3] = elu_(a[3]*inv + bv0[3]);
    o1[0] = elu_(a[4]*inv + bv1[0]);
    o1[1] = elu_(a[5]*inv + bv1[1]);
    o1[2] = elu_(a[6]*inv + bv1[2]);
    o1[3] = elu_(a[7]*inv + bv1[3]);
    *reinterpret_cast<f4*>(&out[(size_t)d*128 + c8])     = o0;
    *reinterpret_cast<f4*>(&out[(size_t)d*128 + c8 + 4]) = o1;
  }
}

// ---------------- global mean pool (batch is sorted) ----------------
__global__ __launch_bounds__(256) void kpool(const float* __restrict__ act,
    const int* __restrict__ batch, int n, float* __restrict__ pool)
{
  __shared__ int sb[2];
  __shared__ float part[128];
  int g = blockIdx.x, tid = threadIdx.x;
  if (tid == 0){
    int lo=0, hi=n;
    while (lo<hi){ int mid=(lo+hi)>>1; if (batch[mid] < g) lo=mid+1; else hi=mid; }
    sb[0]=lo;
    int lo2=lo, hi2=n;
    while (lo2<hi2){ int mid=(lo2+hi2)>>1; if (batch[mid] < g+1) lo2=mid+1; else hi2=mid; }
    sb[1]=lo2;
  }
  __syncthreads();
  int lo=sb[0], hi=sb[1];
  int c = tid & 127, half = tid >> 7;
  float acc = 0.f;
  for (int i=lo+half; i<hi; i+=2) acc += act[(size_t)i*128 + c];
  if (half == 0) part[c] = acc;
  __syncthreads();
  if (half == 1) part[c] += acc;
  __syncthreads();
  if (half == 0){
    float cnt = (float)(hi-lo);
    pool[(size_t)g*128 + c] = part[c] / fmaxf(cnt, 1.f);
  }
}

// ---------------- classifier head ----------------
__global__ __launch_bounds__(64) void kclassify(const float* __restrict__ pool,
    const float* __restrict__ Wc1, const float* __restrict__ bc1,
    const float* __restrict__ Wc2, const float* __restrict__ bc2,
    float* __restrict__ logits)
{
  int g = blockIdx.x, j = threadIdx.x;
  const float* hp = pool + (size_t)g*128;
  float t = bc1[j];
  #pragma unroll 8
  for (int c=0;c<128;c++) t = fmaf(hp[c], Wc1[c*64+j], t);
  t = fmaxf(t, 0.f) * Wc2[j];
  for (int m=1;m<64;m<<=1) t += __shfl_xor(t, m);
  if (j==0) logits[g] = t + bc2[0];
}

extern "C" void kernel_launch(void* const* d_in, const int* in_sizes, int n_in,
                              void* d_out, int out_size, void* d_ws, size_t ws_size,
                              hipStream_t stream)
{
  const int*   x_lex = (const int*)d_in[0];
  const int*   ei    = (const int*)d_in[1];
  const int*   batch = (const int*)d_in[2];
  const float* emb   = (const float*)d_in[3];
  const float* W1    = (const float*)d_in[4];
  const float* a1s   = (const float*)d_in[5];
  const float* a1d   = (const float*)d_in[6];
  const float* b1    = (const float*)d_in[7];
  const float* W2    = (const float*)d_in[8];
  const float* a2s   = (const float*)d_in[9];
  const float* a2d   = (const float*)d_in[10];
  const float* b2    = (const float*)d_in[11];
  const float* Wc1   = (const float*)d_in[12];
  const float* bc1   = (const float*)d_in[13];
  const float* Wc2   = (const float*)d_in[14];
  const float* bc2   = (const float*)d_in[15];

  int N = in_sizes[0];
  int E = in_sizes[1] / 2;
  int Etot = E + N;
  const int G = 256;

  char* p = (char*)d_ws;
  float* hbuf   = (float*)p;          p += (size_t)N*128*4;
  float* act    = (float*)p;          p += (size_t)N*128*4;
  float* als    = (float*)p;          p += (size_t)N*4*4;
  float* ald    = (float*)p;          p += (size_t)N*4*4;
  int*   off    = (int*)p;            p += (size_t)(N+1)*4;
  int*   srcs   = (int*)p;            p += (size_t)Etot*4;
  int*   bbase  = (int*)p;            p += (NBKT+1)*4;
  int*   bcur   = (int*)p;            /* NBKT ints */
  int*   tmp    = (int*)hbuf;         // slabs alias hbuf (CSR build precedes gemm)

  // ---- CSR build (slab bucket sort) ----
  hipMemsetAsync(bcur, 0, NBKT*4, stream);
  int nblk = (Etot + P_CHUNK - 1) / P_CHUNK;
  int nb   = (N + 127) / 128;
  p3scatter<<<nblk,256,0,stream>>>(ei, E, Etot, bcur, tmp);
  p2scan   <<<1,   256,0,stream>>>(bcur, bbase, Etot, off, N);
  p4local  <<<nb,  256,0,stream>>>(tmp, bbase, bcur, off, srcs, N);

  // ---- layer 1: h = emb[x_lex] @ W1, 4 heads ----
  int gb = (N + 63)/64;
  gemm_al<4,true ><<<gb,256,0,stream>>>(emb, x_lex, W1, a1s, a1d, hbuf, als, ald, N);
  aggr<4><<<(N+3)/4,256,0,stream>>>(hbuf, als, ald, srcs, off, b1, act, N);

  // ---- layer 2: h2 = act @ W2, 1 head ----
  gemm_al<1,false><<<gb,256,0,stream>>>(act, nullptr, W2, a2s, a2d, hbuf, als, ald, N);
  aggr<1><<<(N+3)/4,256,0,stream>>>(hbuf, als, ald, srcs, off, b2, act, N);

  // ---- pool + classifier ----
  float* out = (float*)d_out;
  kpool<<<G,256,0,stream>>>(act, batch, N, out + G);
  kclassify<<<G,64,0,stream>>>(out + G, Wc1, bc1, Wc2, bc2, out);
}